// Round 3
// baseline (136.485 us; speedup 1.0000x reference)
//
#include <hip/hip_runtime.h>
#include <hip/hip_bf16.h>

// DEC ClusteringLayer: q[i][j] = (1/(1+||x_i-c_j||^2)) / rowsum, ALPHA=1.
// Barrier-free main loop: B (clusters, 256 KB bf16, L2-resident) is pre-packed in
// fragment order and loaded straight into MFMA operand registers; A (x) is
// self-staged per wave into private LDS (no cross-wave sharing -> no syncthreads
// in the K-loop; DS ops are wave-ordered). Norms fp32, epilogue fused.

typedef __attribute__((ext_vector_type(4))) short short4v;
typedef __attribute__((ext_vector_type(8))) short short8v;
typedef __attribute__((ext_vector_type(4))) float f32x4;

#define DDIM 512
#define KCL  256
#define BM   64
#define NT   512
#define NTILES 16        // DDIM / 32
#define BTILE  8192      // shorts per fragment-order B image (256x32)

__device__ __forceinline__ short f2bf(float f) {
    __hip_bfloat16 h = __float2bfloat16(f);    // RNE; pairs can fuse to v_cvt_pk_bf16_f32
    return __builtin_bit_cast(short, h);
}

// ---- pre-kernel: blocks 0..63 pack clusters -> bf16 fragment-order images;
//      blocks 64..79 compute ||c||^2 ----
__global__ void prep(const float* __restrict__ cl, short* __restrict__ wsB,
                     float* __restrict__ wsC2) {
    const int t = threadIdx.x;
    if (blockIdx.x < 64) {
        const int u = blockIdx.x * 256 + t;            // granule id
        const int img = u >> 10, gi = u & 1023;
        const int g = gi >> 6, lq = (gi >> 4) & 3, l15 = gi & 15;
        const float* src = cl + (size_t)(g * 16 + l15) * DDIM + img * 32 + lq * 8;
        float4 a = *(const float4*)src;
        float4 b = *(const float4*)(src + 4);
        short8v s;
        s[0]=f2bf(a.x); s[1]=f2bf(a.y); s[2]=f2bf(a.z); s[3]=f2bf(a.w);
        s[4]=f2bf(b.x); s[5]=f2bf(b.y); s[6]=f2bf(b.z); s[7]=f2bf(b.w);
        *(short8v*)&wsB[(size_t)u * 8] = s;
    } else {
        const int cidx = (blockIdx.x - 64) * 16 + (t >> 4);
        const int j = t & 15;
        const float* src = cl + (size_t)cidx * DDIM + j * 32;
        float s = 0.f;
#pragma unroll
        for (int i = 0; i < 8; ++i) {
            float4 v = ((const float4*)src)[i];
            s += v.x*v.x + v.y*v.y + v.z*v.z + v.w*v.w;
        }
        s += __shfl_xor(s, 1); s += __shfl_xor(s, 2);
        s += __shfl_xor(s, 4); s += __shfl_xor(s, 8);
        if (j == 0) wsC2[cidx] = s;
    }
}

// ---- main: 64 rows x 256 clusters per block, 8 waves (2 row-grp x 4 col-grp) ----
__global__ __launch_bounds__(NT, 4)
void dec_main(const float* __restrict__ x, const short* __restrict__ wsB,
              const float* __restrict__ wsC2, float* __restrict__ out) {
    __shared__ __align__(16) short lA[8][4][1024];   // per-wave 4 private 2KB bufs (64 KB)
    __shared__ float s_x2[BM];
    __shared__ float s_rs[4][BM];

    const int t = threadIdx.x, lane = t & 63, w = t >> 6;
    const int rg = w >> 2, cg = w & 3;
    const int l15 = lane & 15, lq = lane >> 4;
    const int rsub = lane >> 2, q4 = lane & 3;       // staging: 4 lanes per row
    const int row0 = blockIdx.x * BM;

    // A global base: lane covers rows (rg*32 + rb*16 + rsub), floats q4*4 + j*16
    const float* xb0 = x + (size_t)(row0 + rg*32 + rsub) * DDIM + q4*4;
    const float* xb1 = xb0 + (size_t)16 * DDIM;
    // B fragment base: image tt, fragment n -> bb + tt*BTILE + n*512
    const short* bb = wsB + (size_t)(cg*4) * 512 + (size_t)lane * 8;
    short* const myA = &lA[w][0][0];
    const int cs  = (rsub & 3) << 3;                 // staging swizzle
    const int fs0 = (lq * 8) ^ ((l15 & 3) << 3);     // fragment-read swizzled k-chunk

    f32x4 acc[2][4];
#pragma unroll
    for (int m = 0; m < 2; ++m)
#pragma unroll
        for (int n = 0; n < 4; ++n) acc[m][n] = (f32x4){0.f,0.f,0.f,0.f};
    float x2a = 0.f, x2b = 0.f;

    short8v B[2][4];
    float4 xv[2][4];

#define LOADB(tt, slot)                                                          \
    {  _Pragma("unroll")                                                         \
       for (int n = 0; n < 4; ++n)                                              \
           B[slot][n] = *(const short8v*)(bb + (size_t)(tt) * BTILE + n * 512); }

#define LOADX(tt, slot)                                                          \
    {  xv[slot][0] = *(const float4*)(xb0 + (tt) * 32);                          \
       xv[slot][1] = *(const float4*)(xb0 + (tt) * 32 + 16);                     \
       xv[slot][2] = *(const float4*)(xb1 + (tt) * 32);                          \
       xv[slot][3] = *(const float4*)(xb1 + (tt) * 32 + 16); }

#define CVTW(buf, slot)                                                          \
    {  short* dst = myA + (buf) * 1024;                                          \
       float4 a = xv[slot][0], b2 = xv[slot][1], c = xv[slot][2], d = xv[slot][3];\
       short4v sa, sb, sc, sd;                                                   \
       sa[0]=f2bf(a.x); sa[1]=f2bf(a.y); sa[2]=f2bf(a.z); sa[3]=f2bf(a.w);       \
       sb[0]=f2bf(b2.x); sb[1]=f2bf(b2.y); sb[2]=f2bf(b2.z); sb[3]=f2bf(b2.w);   \
       sc[0]=f2bf(c.x); sc[1]=f2bf(c.y); sc[2]=f2bf(c.z); sc[3]=f2bf(c.w);       \
       sd[0]=f2bf(d.x); sd[1]=f2bf(d.y); sd[2]=f2bf(d.z); sd[3]=f2bf(d.w);       \
       *(short4v*)&dst[rsub*32        + ((q4*4)      ^ cs)] = sa;                \
       *(short4v*)&dst[rsub*32        + ((16 + q4*4) ^ cs)] = sb;                \
       *(short4v*)&dst[(16+rsub)*32   + ((q4*4)      ^ cs)] = sc;                \
       *(short4v*)&dst[(16+rsub)*32   + ((16 + q4*4) ^ cs)] = sd;                \
       x2a += a.x*a.x + a.y*a.y + a.z*a.z + a.w*a.w                              \
            + b2.x*b2.x + b2.y*b2.y + b2.z*b2.z + b2.w*b2.w;                     \
       x2b += c.x*c.x + c.y*c.y + c.z*c.z + c.w*c.w                              \
            + d.x*d.x + d.y*d.y + d.z*d.z + d.w*d.w; }

    // prologue: B(0),B(1) + stage tiles 0,1; x(2),x(3) in flight
    LOADB(0, 0);
    LOADX(0, 0); LOADX(1, 1);
    LOADB(1, 1);
    CVTW(0, 0); CVTW(1, 1);
    LOADX(2, 0); LOADX(3, 1);

#pragma unroll
    for (int tt = 0; tt < NTILES; ++tt) {
        const short* buf = myA + (tt & 3) * 1024;
        short8v a0 = *(const short8v*)&buf[(l15)      * 32 + fs0];
        short8v a1 = *(const short8v*)&buf[(16 + l15) * 32 + fs0];
        const int sl = tt & 1;
        acc[0][0] = __builtin_amdgcn_mfma_f32_16x16x32_bf16(a0, B[sl][0], acc[0][0], 0,0,0);
        acc[0][1] = __builtin_amdgcn_mfma_f32_16x16x32_bf16(a0, B[sl][1], acc[0][1], 0,0,0);
        acc[0][2] = __builtin_amdgcn_mfma_f32_16x16x32_bf16(a0, B[sl][2], acc[0][2], 0,0,0);
        acc[0][3] = __builtin_amdgcn_mfma_f32_16x16x32_bf16(a0, B[sl][3], acc[0][3], 0,0,0);
        acc[1][0] = __builtin_amdgcn_mfma_f32_16x16x32_bf16(a1, B[sl][0], acc[1][0], 0,0,0);
        acc[1][1] = __builtin_amdgcn_mfma_f32_16x16x32_bf16(a1, B[sl][1], acc[1][1], 0,0,0);
        acc[1][2] = __builtin_amdgcn_mfma_f32_16x16x32_bf16(a1, B[sl][2], acc[1][2], 0,0,0);
        acc[1][3] = __builtin_amdgcn_mfma_f32_16x16x32_bf16(a1, B[sl][3], acc[1][3], 0,0,0);
        if (tt + 2 < NTILES) {
            LOADB(tt + 2, sl);                 // slot's old tile just consumed
            CVTW((tt + 2) & 3, sl);            // stage A(tt+2) (loads from iter tt-2)
        }
        if (tt + 4 < NTILES) LOADX(tt + 4, sl);
    }

    // ---- ||x||^2: quartet shuffle-reduce; cg==0 waves publish ----
    x2a += __shfl_xor(x2a, 1); x2a += __shfl_xor(x2a, 2);
    x2b += __shfl_xor(x2b, 1); x2b += __shfl_xor(x2b, 2);
    if (cg == 0 && q4 == 0) {
        s_x2[rg*32 + rsub]      = x2a;
        s_x2[rg*32 + 16 + rsub] = x2b;
    }
    __syncthreads();

    // ---- epilogue: d2 -> q_unnorm (C/D: col=l15, row=lq*4+r) ----
    float c2a[4];
#pragma unroll
    for (int n = 0; n < 4; ++n) c2a[n] = wsC2[cg*64 + n*16 + l15];

#pragma unroll
    for (int m = 0; m < 2; ++m)
#pragma unroll
        for (int n = 0; n < 4; ++n)
#pragma unroll
            for (int r = 0; r < 4; ++r) {
                const int rw = rg*32 + m*16 + lq*4 + r;
                float d2 = fmaxf(s_x2[rw] + c2a[n] - 2.0f * acc[m][n][r], 0.0f);
                acc[m][n][r] = 1.0f / (1.0f + d2);
            }

    // ---- row sums: 16-lane shuffle, per-cg slot (deterministic) ----
#pragma unroll
    for (int m = 0; m < 2; ++m)
#pragma unroll
        for (int r = 0; r < 4; ++r) {
            float p = acc[m][0][r] + acc[m][1][r] + acc[m][2][r] + acc[m][3][r];
            p += __shfl_xor(p, 1); p += __shfl_xor(p, 2);
            p += __shfl_xor(p, 4); p += __shfl_xor(p, 8);
            if (l15 == 0) s_rs[cg][rg*32 + m*16 + lq*4 + r] = p;
        }
    __syncthreads();

    // ---- normalize + store ----
#pragma unroll
    for (int m = 0; m < 2; ++m)
#pragma unroll
        for (int r = 0; r < 4; ++r) {
            const int rw = rg*32 + m*16 + lq*4 + r;
            const float rinv = 1.0f / (s_rs[0][rw] + s_rs[1][rw] + s_rs[2][rw] + s_rs[3][rw]);
            float* o = out + (size_t)(row0 + rw) * KCL + cg*64 + l15;
#pragma unroll
            for (int n = 0; n < 4; ++n)
                o[n * 16] = acc[m][n][r] * rinv;
        }
}

extern "C" void kernel_launch(void* const* d_in, const int* in_sizes, int n_in,
                              void* d_out, int out_size, void* d_ws, size_t ws_size,
                              hipStream_t stream) {
    const float* x  = (const float*)d_in[0];
    const float* cl = (const float*)d_in[1];
    float* out = (float*)d_out;
    short* wsB  = (short*)d_ws;
    float* wsC2 = (float*)((char*)d_ws + (size_t)NTILES * BTILE * sizeof(short)); // +256 KB

    prep<<<80, 256, 0, stream>>>(cl, wsB, wsC2);
    const int B = in_sizes[0] / DDIM;     // 65536
    dec_main<<<B / BM, NT, 0, stream>>>(x, wsB, wsC2, out);
}

// Round 4
// 90.387 us; speedup vs baseline: 1.5100x; 1.5100x over previous
//
#include <hip/hip_runtime.h>
#include <hip/hip_bf16.h>

// DEC ClusteringLayer: q[i][j] = (1/(1+||x_i-c_j||^2)) / rowsum, ALPHA=1.
// Fully barrier-free, LDS-free K-loop: A fragments are loaded per-lane straight
// from global x (fragment layout == natural per-lane load) and converted fp32->bf16
// in registers; B (clusters, 256 KB bf16, L2/L1-resident) is pre-packed in fragment
// order and loaded straight into MFMA operands. All prefetch buffers use literal
// indices only (rule #20: no runtime-indexed ext_vector arrays -> no scratch).

typedef __attribute__((ext_vector_type(8))) short short8v;
typedef __attribute__((ext_vector_type(4))) float f32x4;

#define DDIM 512
#define KCL  256
#define BM   64
#define NT   512
#define NTILES 16        // DDIM / 32
#define BTILE  8192      // shorts per fragment-order B image (256x32)

__device__ __forceinline__ short f2bf(float f) {
    __hip_bfloat16 h = __float2bfloat16(f);
    return __builtin_bit_cast(short, h);
}

// ---- pre-kernel: blocks 0..63 pack clusters -> bf16 fragment-order images;
//      blocks 64..79 compute ||c||^2 ----
__global__ void prep(const float* __restrict__ cl, short* __restrict__ wsB,
                     float* __restrict__ wsC2) {
    const int t = threadIdx.x;
    if (blockIdx.x < 64) {
        const int u = blockIdx.x * 256 + t;            // granule id
        const int img = u >> 10, gi = u & 1023;
        const int g = gi >> 6, lq = (gi >> 4) & 3, l15 = gi & 15;
        const float* src = cl + (size_t)(g * 16 + l15) * DDIM + img * 32 + lq * 8;
        float4 a = *(const float4*)src;
        float4 b = *(const float4*)(src + 4);
        short8v s;
        s[0]=f2bf(a.x); s[1]=f2bf(a.y); s[2]=f2bf(a.z); s[3]=f2bf(a.w);
        s[4]=f2bf(b.x); s[5]=f2bf(b.y); s[6]=f2bf(b.z); s[7]=f2bf(b.w);
        *(short8v*)&wsB[(size_t)u * 8] = s;
    } else {
        const int cidx = (blockIdx.x - 64) * 16 + (t >> 4);
        const int j = t & 15;
        const float* src = cl + (size_t)cidx * DDIM + j * 32;
        float s = 0.f;
#pragma unroll
        for (int i = 0; i < 8; ++i) {
            float4 v = ((const float4*)src)[i];
            s += v.x*v.x + v.y*v.y + v.z*v.z + v.w*v.w;
        }
        s += __shfl_xor(s, 1); s += __shfl_xor(s, 2);
        s += __shfl_xor(s, 4); s += __shfl_xor(s, 8);
        if (j == 0) wsC2[cidx] = s;
    }
}

// ---- main: 64 rows x 256 clusters per block, 8 waves (2 row-grp x 4 col-grp) ----
__global__ __launch_bounds__(NT, 4)
void dec_main(const float* __restrict__ x, const short* __restrict__ wsB,
              const float* __restrict__ wsC2, float* __restrict__ out) {
    __shared__ float s_x2[BM];
    __shared__ float s_rs[4][BM];

    const int t = threadIdx.x, lane = t & 63, w = t >> 6;
    const int rg = w >> 2, cg = w & 3;
    const int l15 = lane & 15, lq = lane >> 4;
    const int row0 = blockIdx.x * BM;

    // per-lane A sources: row rg*32 + l15 (frag a0) and +16 (frag a1), cols lq*8..+7
    const float* xr0 = x + (size_t)(row0 + rg*32 + l15) * DDIM + lq * 8;
    const float* xr1 = xr0 + (size_t)16 * DDIM;
    // B fragment base: image tt at bb + tt*BTILE, fragment n at + n*512
    const short* bb = wsB + (size_t)(cg*4) * 512 + (size_t)lane * 8;

    f32x4 acc[2][4];
#pragma unroll
    for (int m = 0; m < 2; ++m)
#pragma unroll
        for (int n = 0; n < 4; ++n) acc[m][n] = (f32x4){0.f,0.f,0.f,0.f};
    float x2a = 0.f, x2b = 0.f;

    short8v Bc[4];
    float4 Xc[4], Xn[4];

#define LOADX(TT, XB)                                        \
    {  XB[0] = *(const float4*)(xr0 + (TT) * 32);            \
       XB[1] = *(const float4*)(xr0 + (TT) * 32 + 4);        \
       XB[2] = *(const float4*)(xr1 + (TT) * 32);            \
       XB[3] = *(const float4*)(xr1 + (TT) * 32 + 4); }

    // body: consume XB (tile TT), prefetch tile PT into XB, B loaded at top
#define BODY(TT, XB, PT)                                                         \
    {  const short* bt = bb + (size_t)(TT) * BTILE;                              \
       Bc[0] = *(const short8v*)(bt);                                            \
       Bc[1] = *(const short8v*)(bt + 512);                                      \
       Bc[2] = *(const short8v*)(bt + 1024);                                     \
       Bc[3] = *(const short8v*)(bt + 1536);                                     \
       short8v a0, a1;                                                           \
       {  float4 p = XB[0], q = XB[1], r2 = XB[2], s2 = XB[3];                   \
          a0[0]=f2bf(p.x); a0[1]=f2bf(p.y); a0[2]=f2bf(p.z); a0[3]=f2bf(p.w);    \
          a0[4]=f2bf(q.x); a0[5]=f2bf(q.y); a0[6]=f2bf(q.z); a0[7]=f2bf(q.w);    \
          a1[0]=f2bf(r2.x); a1[1]=f2bf(r2.y); a1[2]=f2bf(r2.z); a1[3]=f2bf(r2.w);\
          a1[4]=f2bf(s2.x); a1[5]=f2bf(s2.y); a1[6]=f2bf(s2.z); a1[7]=f2bf(s2.w);\
          x2a += p.x*p.x + p.y*p.y + p.z*p.z + p.w*p.w                           \
               + q.x*q.x + q.y*q.y + q.z*q.z + q.w*q.w;                          \
          x2b += r2.x*r2.x + r2.y*r2.y + r2.z*r2.z + r2.w*r2.w                   \
               + s2.x*s2.x + s2.y*s2.y + s2.z*s2.z + s2.w*s2.w; }                \
       if ((PT) < NTILES) LOADX(PT, XB);                                         \
       acc[0][0] = __builtin_amdgcn_mfma_f32_16x16x32_bf16(a0, Bc[0], acc[0][0], 0,0,0); \
       acc[0][1] = __builtin_amdgcn_mfma_f32_16x16x32_bf16(a0, Bc[1], acc[0][1], 0,0,0); \
       acc[0][2] = __builtin_amdgcn_mfma_f32_16x16x32_bf16(a0, Bc[2], acc[0][2], 0,0,0); \
       acc[0][3] = __builtin_amdgcn_mfma_f32_16x16x32_bf16(a0, Bc[3], acc[0][3], 0,0,0); \
       acc[1][0] = __builtin_amdgcn_mfma_f32_16x16x32_bf16(a1, Bc[0], acc[1][0], 0,0,0); \
       acc[1][1] = __builtin_amdgcn_mfma_f32_16x16x32_bf16(a1, Bc[1], acc[1][1], 0,0,0); \
       acc[1][2] = __builtin_amdgcn_mfma_f32_16x16x32_bf16(a1, Bc[2], acc[1][2], 0,0,0); \
       acc[1][3] = __builtin_amdgcn_mfma_f32_16x16x32_bf16(a1, Bc[3], acc[1][3], 0,0,0); }

    // prologue: x tiles 0 and 1 in flight
    LOADX(0, Xc);
    LOADX(1, Xn);

#pragma unroll
    for (int tt = 0; tt < NTILES; tt += 2) {
        BODY(tt,     Xc, tt + 2);
        BODY(tt + 1, Xn, tt + 3);
    }

    // ---- ||x||^2: lanes sharing l15 (lq=0..3) hold disjoint k-ranges ----
    x2a += __shfl_xor(x2a, 16); x2a += __shfl_xor(x2a, 32);
    x2b += __shfl_xor(x2b, 16); x2b += __shfl_xor(x2b, 32);
    if (cg == 0 && lq == 0) {
        s_x2[rg*32 + l15]      = x2a;
        s_x2[rg*32 + 16 + l15] = x2b;
    }
    __syncthreads();

    // ---- epilogue: d2 -> q_unnorm (C/D: col=l15, row=lq*4+r) ----
    float c2a[4];
#pragma unroll
    for (int n = 0; n < 4; ++n) c2a[n] = wsC2[cg*64 + n*16 + l15];

#pragma unroll
    for (int m = 0; m < 2; ++m)
#pragma unroll
        for (int n = 0; n < 4; ++n)
#pragma unroll
            for (int r = 0; r < 4; ++r) {
                const int rw = rg*32 + m*16 + lq*4 + r;
                float d2 = fmaxf(s_x2[rw] + c2a[n] - 2.0f * acc[m][n][r], 0.0f);
                acc[m][n][r] = 1.0f / (1.0f + d2);
            }

    // ---- row sums: 16-lane shuffle, per-cg slot (deterministic) ----
#pragma unroll
    for (int m = 0; m < 2; ++m)
#pragma unroll
        for (int r = 0; r < 4; ++r) {
            float p = acc[m][0][r] + acc[m][1][r] + acc[m][2][r] + acc[m][3][r];
            p += __shfl_xor(p, 1); p += __shfl_xor(p, 2);
            p += __shfl_xor(p, 4); p += __shfl_xor(p, 8);
            if (l15 == 0) s_rs[cg][rg*32 + m*16 + lq*4 + r] = p;
        }
    __syncthreads();

    // ---- normalize + store ----
#pragma unroll
    for (int m = 0; m < 2; ++m)
#pragma unroll
        for (int r = 0; r < 4; ++r) {
            const int rw = rg*32 + m*16 + lq*4 + r;
            const float rinv = 1.0f / (s_rs[0][rw] + s_rs[1][rw] + s_rs[2][rw] + s_rs[3][rw]);
            float* o = out + (size_t)(row0 + rw) * KCL + cg*64 + l15;
#pragma unroll
            for (int n = 0; n < 4; ++n)
                o[n * 16] = acc[m][n][r] * rinv;
        }
}

extern "C" void kernel_launch(void* const* d_in, const int* in_sizes, int n_in,
                              void* d_out, int out_size, void* d_ws, size_t ws_size,
                              hipStream_t stream) {
    const float* x  = (const float*)d_in[0];
    const float* cl = (const float*)d_in[1];
    float* out = (float*)d_out;
    short* wsB  = (short*)d_ws;
    float* wsC2 = (float*)((char*)d_ws + (size_t)NTILES * BTILE * sizeof(short)); // +256 KB

    prep<<<80, 256, 0, stream>>>(cl, wsB, wsC2);
    const int B = in_sizes[0] / DDIM;     // 65536
    dec_main<<<B / BM, NT, 0, stream>>>(x, wsB, wsC2, out);
}